// Round 6
// baseline (296.050 us; speedup 1.0000x reference)
//
#include <hip/hip_runtime.h>
#include <math.h>

#define F_IN 128
#define HID  64
#define NH   4
#define DD   16
#define CC   16
#define CSTE 1e-5f

typedef _Float16 h2     __attribute__((ext_vector_type(2)));
typedef float    f2     __attribute__((ext_vector_type(2)));
typedef short    short8 __attribute__((ext_vector_type(8)));
typedef float    f4v    __attribute__((ext_vector_type(4)));

// LDS strides (elements) — padded so b128 frag reads are ≤2-way bank conflicts
#define WIT_LD 136
#define W2T_LD 72
#define H_LD   72

__device__ __forceinline__ unsigned short bf16r(float f) {
    unsigned int u = __builtin_bit_cast(unsigned int, f);
    unsigned int r = (u + 0x7FFFu + ((u >> 16) & 1u)) >> 16;
    return (unsigned short)r;
}

// wave-uniform hint: value is identical across the wave; moves it to SGPR so
// loop control / index loads / base addresses go to the SALU+SMEM pipes
// (parallel to VALU) instead of 64-lane vector address math.
__device__ __forceinline__ int uni(int v) {
    return __builtin_amdgcn_readfirstlane(v);
}

// ---------------- fp8 scalar helpers (OCP e4m3 via hw cvt) ----------------
__device__ __forceinline__ float fp8_to_f32(unsigned int b) {
    f2 v = __builtin_amdgcn_cvt_pk_f32_fp8((int)b, false);
    return v.x;
}
__device__ __forceinline__ f2 fp8x2_to_f32(unsigned int w) {   // {lo, hi} in one op
    return __builtin_amdgcn_cvt_pk_f32_fp8((int)w, false);
}
__device__ __forceinline__ unsigned char f32_to_fp8(float f) {
    int w = __builtin_amdgcn_cvt_pk_fp8_f32(f, f, 0, false);
    return (unsigned char)(w & 0xff);
}

// ---------------- fp4 e2m1 helpers ----------------
__device__ __forceinline__ float fp4_dec1(unsigned int n) {
    unsigned int e = (n >> 1) & 3u, m = n & 1u;
    float mag = (e == 0) ? 0.5f * (float)m
                         : (float)(1u << (e - 1)) * (1.0f + 0.5f * (float)m);
    return (n & 8u) ? -mag : mag;
}
__device__ __forceinline__ unsigned int fp4_enc1(float f) {
    unsigned int s = (f < 0.f) ? 8u : 0u;
    float a = fabsf(f);
    unsigned int m;
    if      (a < 0.25f) m = 0u;
    else if (a < 0.75f) m = 1u;
    else if (a < 1.25f) m = 2u;
    else if (a < 1.75f) m = 3u;
    else if (a < 2.5f)  m = 4u;
    else if (a < 3.5f)  m = 5u;
    else if (a < 5.0f)  m = 6u;
    else                m = 7u;
    return s | m;
}

#if __has_builtin(__builtin_amdgcn_cvt_scalef32_pk_f32_fp4) && __has_builtin(__builtin_amdgcn_cvt_scalef32_pk_fp4_f32)
#define HAS_FP4 1
#endif

// decode 16 fp4 nibbles into 8 packed f2 pairs (natural order)
__device__ __forceinline__ void fp4x16_dec2(unsigned int wx, unsigned int wy, f2* v) {
#ifdef HAS_FP4
    v[0] = __builtin_amdgcn_cvt_scalef32_pk_f32_fp4(wx, 1.0f, 0);
    v[1] = __builtin_amdgcn_cvt_scalef32_pk_f32_fp4(wx, 1.0f, 1);
    v[2] = __builtin_amdgcn_cvt_scalef32_pk_f32_fp4(wx, 1.0f, 2);
    v[3] = __builtin_amdgcn_cvt_scalef32_pk_f32_fp4(wx, 1.0f, 3);
    v[4] = __builtin_amdgcn_cvt_scalef32_pk_f32_fp4(wy, 1.0f, 0);
    v[5] = __builtin_amdgcn_cvt_scalef32_pk_f32_fp4(wy, 1.0f, 1);
    v[6] = __builtin_amdgcn_cvt_scalef32_pk_f32_fp4(wy, 1.0f, 2);
    v[7] = __builtin_amdgcn_cvt_scalef32_pk_f32_fp4(wy, 1.0f, 3);
#else
    #pragma unroll
    for (int j = 0; j < 4; ++j) {
        v[j].x     = fp4_dec1((wx >> (8 * j)) & 0xFu);
        v[j].y     = fp4_dec1((wx >> (8 * j + 4)) & 0xFu);
        v[4 + j].x = fp4_dec1((wy >> (8 * j)) & 0xFu);
        v[4 + j].y = fp4_dec1((wy >> (8 * j + 4)) & 0xFu);
    }
#endif
}

__device__ __forceinline__ uint2 fp4x16_enc(const float* v) {
#ifdef HAS_FP4
    unsigned int a = 0u, b = 0u;
    a = __builtin_amdgcn_cvt_scalef32_pk_fp4_f32(a, v[0],  v[1],  1.0f, 0);
    a = __builtin_amdgcn_cvt_scalef32_pk_fp4_f32(a, v[2],  v[3],  1.0f, 1);
    a = __builtin_amdgcn_cvt_scalef32_pk_fp4_f32(a, v[4],  v[5],  1.0f, 2);
    a = __builtin_amdgcn_cvt_scalef32_pk_fp4_f32(a, v[6],  v[7],  1.0f, 3);
    b = __builtin_amdgcn_cvt_scalef32_pk_fp4_f32(b, v[8],  v[9],  1.0f, 0);
    b = __builtin_amdgcn_cvt_scalef32_pk_fp4_f32(b, v[10], v[11], 1.0f, 1);
    b = __builtin_amdgcn_cvt_scalef32_pk_fp4_f32(b, v[12], v[13], 1.0f, 2);
    b = __builtin_amdgcn_cvt_scalef32_pk_fp4_f32(b, v[14], v[15], 1.0f, 3);
    return {a, b};
#else
    unsigned int a = 0u, b = 0u;
    #pragma unroll
    for (int j = 0; j < 8; ++j) {
        a |= fp4_enc1(v[j])     << (4 * j);
        b |= fp4_enc1(v[8 + j]) << (4 * j);
    }
    return {a, b};
#endif
}

// packed M record: per node 64 lanes × 12B {fp4 payload lo, hi, (scale|K<<8)}.
// One dwordx3 load per edge per lane (was 2 loads: 8B M + 2B SK).
// store one M row into the packed record
__device__ __forceinline__ void store_m_row(
    uint3* __restrict__ rec, int node, int lane, const float* u, float kacc)
{
    float rm = 0.f;
    #pragma unroll
    for (int j = 0; j < 16; ++j) rm = fmaxf(rm, fabsf(u[j]));
    unsigned char s8 = f32_to_fp8(rm * (1.0f / 6.0f));
    float se = fp8_to_f32((unsigned int)s8);
    float invs = (se > 0.f) ? (1.0f / se) : 0.f;
    float tq[16];
    #pragma unroll
    for (int j = 0; j < 16; ++j) tq[j] = u[j] * invs;
    uint2 enc = fp4x16_enc(tq);
    unsigned int sk = (unsigned int)s8 | ((unsigned int)f32_to_fp8(kacc) << 8);
    rec[(size_t)node * 64 + lane] = {enc.x, enc.y, sk};
}

// per-hop gamma (hop>=1): hopwise[hop] * softmax_over_heads(temp[:,hop])[h]
__device__ __forceinline__ float gamma_for(const float* __restrict__ temp,
                                           const float* __restrict__ hopwise,
                                           int h, int hop) {
    float t0 = temp[0 * 4 + hop], t1 = temp[1 * 4 + hop];
    float t2 = temp[2 * 4 + hop], t3 = temp[3 * 4 + hop];
    float mx = fmaxf(fmaxf(t0, t1), fmaxf(t2, t3));
    float e0 = __expf(t0 - mx), e1 = __expf(t1 - mx);
    float e2 = __expf(t2 - mx), e3 = __expf(t3 - mx);
    float ssum = e0 + e1 + e2 + e3;
    float eh = (h == 0) ? e0 : (h == 1) ? e1 : (h == 2) ? e2 : e3;
    return hopwise[hop] * eh / ssum;
}

// reduce-scatter over the 16 lanes of a head: u[j] holds column j (natural);
// afterwards lane p holds, in u[0], the group sum for column p.
__device__ __forceinline__ void reduce_scatter16(float* u, int p) {
    #pragma unroll
    for (int k = 0; k < 4; ++k) {
        const int m = 1 << k;
        bool bit = (p >> k) & 1;
        const int n = 8 >> k;
        #pragma unroll
        for (int j = 0; j < n; ++j) {
            float give = bit ? u[2 * j]     : u[2 * j + 1];
            float keep = bit ? u[2 * j + 1] : u[2 * j];
            float got  = __shfl_xor(give, m, 64);
            u[j] = keep + got;
        }
    }
}

// den = sum over the 16-lane group of qd*kacc, plus CST
__device__ __forceinline__ float den16(float qd, float kacc) {
    float kq = qd * kacc;
    kq += __shfl_xor(kq, 1, 64);
    kq += __shfl_xor(kq, 2, 64);
    kq += __shfl_xor(kq, 4, 64);
    kq += __shfl_xor(kq, 8, 64);
    return kq + CSTE;
}

// per-edge accumulate for hops 2/3 from a packed 12B record
__device__ __forceinline__ void acc_edge23(f2* u2, float& kacc, uint3 w) {
    f2 sk = fp8x2_to_f32(w.z);         // low byte = scale, high byte = K
    kacc += sk.y;
    f2 v[8];
    fp4x16_dec2(w.x, w.y, v);
    f2 s = {sk.x, sk.x};
    #pragma unroll
    for (int j = 0; j < 8; ++j) u2[j] = s * v[j] + u2[j];
}

// per-edge accumulate for hop 1: u16 += K * V (fp16x2)
__device__ __forceinline__ void acc_edge1(h2* u16, float& kacc,
                                          uint4 a0, uint4 a1, unsigned int kraw) {
    float kk = fp8_to_f32(kraw);
    kacc += kk;
    _Float16 kh = (_Float16)kk;
    h2 k2 = {kh, kh};
    const unsigned int aw[8] = {a0.x, a0.y, a0.z, a0.w, a1.x, a1.y, a1.z, a1.w};
    #pragma unroll
    for (int j = 0; j < 8; ++j)
        u16[j] += k2 * __builtin_bit_cast(h2, aw[j]);
}

// ---------------- CSR scan ----------------
__global__ __launch_bounds__(1024) void scan_a(const int* __restrict__ deg,
                                               int* __restrict__ offsets,
                                               int* __restrict__ bsum, int N) {
    __shared__ int wsum[16], woff[16];
    int lane = threadIdx.x & 63, w = threadIdx.x >> 6;
    int i0 = blockIdx.x * 4096 + (int)threadIdx.x * 4;
    int d0 = (i0 + 0 < N) ? deg[i0 + 0] : 0;
    int d1 = (i0 + 1 < N) ? deg[i0 + 1] : 0;
    int d2 = (i0 + 2 < N) ? deg[i0 + 2] : 0;
    int d3 = (i0 + 3 < N) ? deg[i0 + 3] : 0;
    int tsum = d0 + d1 + d2 + d3;
    int incl = tsum;
    #pragma unroll
    for (int m = 1; m < 64; m <<= 1) {
        int t = __shfl_up(incl, m, 64);
        if (lane >= m) incl += t;
    }
    if (lane == 63) wsum[w] = incl;
    __syncthreads();
    if (threadIdx.x == 0) {
        int r = 0;
        for (int k = 0; k < 16; ++k) { int t = wsum[k]; woff[k] = r; r += t; }
        bsum[blockIdx.x] = r;
    }
    __syncthreads();
    int excl = woff[w] + incl - tsum;
    if (i0 + 0 < N) offsets[i0 + 0] = excl;
    if (i0 + 1 < N) offsets[i0 + 1] = excl + d0;
    if (i0 + 2 < N) offsets[i0 + 2] = excl + d0 + d1;
    if (i0 + 3 < N) offsets[i0 + 3] = excl + d0 + d1 + d2;
}

__global__ void scan_c(int* __restrict__ offsets, const int* __restrict__ bsum,
                       int nb, int N) {
    int i = blockIdx.x * blockDim.x + threadIdx.x;
    if (i < N) {
        int bkt = i >> 12;
        int base = 0;
        for (int b = 0; b < bkt; ++b) base += bsum[b];
        offsets[i] += base;
    }
    if (i == 0) {
        int tot = 0;
        for (int b = 0; b < nb; ++b) tot += bsum[b];
        offsets[N] = tot;
    }
}

__global__ void scatter_kernel(const int* __restrict__ ei, const int* __restrict__ offsets,
                               int* __restrict__ cursor, int* __restrict__ csr, int E) {
    int e = blockIdx.x * blockDim.x + threadIdx.x;
    if (e < E) {
        int src = ei[e];
        int dst = ei[E + e];
        int pos = atomicAdd(&cursor[dst], 1);
        csr[offsets[dst] + pos] = src;
    }
}

// ---------------- fused MFMA QKV + edge counting ----------------
// blocks [0, qb): qkv (64 nodes/block); blocks [qb, qb+eb): degree count
__global__ __launch_bounds__(256) void qkv_count(
    const float* __restrict__ x,
    const float* __restrict__ Wi, const float* __restrict__ bi,
    const float* __restrict__ Wq, const float* __restrict__ bq,
    const float* __restrict__ Wk, const float* __restrict__ bk,
    const float* __restrict__ Wv, const float* __restrict__ bv,
    float* __restrict__ Q, unsigned char* __restrict__ K0,
    _Float16* __restrict__ Vh,
    const int* __restrict__ ei, int* __restrict__ deg,
    int E, int qb, int N)
{
    __shared__ unsigned short wit[64 * WIT_LD];
    __shared__ unsigned short w2t[192 * W2T_LD];
    __shared__ unsigned short hlds[64 * H_LD];
    if ((int)blockIdx.x >= qb) {
        int e = ((int)blockIdx.x - qb) * 256 + (int)threadIdx.x;
        if (e < E) atomicAdd(&deg[ei[E + e]], 1);   // dst = ei[1][e]
        return;
    }
    int t = threadIdx.x;
    #pragma unroll
    for (int i = 0; i < 32; ++i) {
        int g = t + i * 256;                       // 8192 = 128*64
        wit[(g & 63) * WIT_LD + (g >> 6)] = bf16r(Wi[g]);
    }
    #pragma unroll
    for (int i = 0; i < 16; ++i) {
        int g = t + i * 256;                       // 4096 = 64*64
        int k = g >> 6, n = g & 63;
        w2t[(n      ) * W2T_LD + k] = bf16r(Wq[g]);
        w2t[(n +  64) * W2T_LD + k] = bf16r(Wk[g]);
        w2t[(n + 128) * W2T_LD + k] = bf16r(Wv[g]);
    }
    __syncthreads();

    int lane = t & 63, w = t >> 6;
    int p = lane & 15, quad = lane >> 4;
    int mbase = blockIdx.x * 64 + w * 16;

    // ---- stage 1: h = relu(x@Wi + bi) ----
    short8 afrag[4];
    {
        int node = mbase + p;
        if (node >= N) node = N - 1;               // clamped read; stores guarded
        const float* xr = x + (size_t)node * F_IN + quad * 8;
        #pragma unroll
        for (int ks = 0; ks < 4; ++ks) {
            float4 a0 = *(const float4*)(xr + ks * 32);
            float4 a1 = *(const float4*)(xr + ks * 32 + 4);
            short8 f;
            f[0] = bf16r(a0.x); f[1] = bf16r(a0.y); f[2] = bf16r(a0.z); f[3] = bf16r(a0.w);
            f[4] = bf16r(a1.x); f[5] = bf16r(a1.y); f[6] = bf16r(a1.z); f[7] = bf16r(a1.w);
            afrag[ks] = f;
        }
    }
    #pragma unroll
    for (int nt = 0; nt < 4; ++nt) {
        f4v acc = {0.f, 0.f, 0.f, 0.f};
        #pragma unroll
        for (int ks = 0; ks < 4; ++ks) {
            short8 b = *(const short8*)&wit[(nt * 16 + p) * WIT_LD + ks * 32 + quad * 8];
            acc = __builtin_amdgcn_mfma_f32_16x16x32_bf16(afrag[ks], b, acc, 0, 0, 0);
        }
        float bb = bi[nt * 16 + p];
        #pragma unroll
        for (int r = 0; r < 4; ++r) {
            float hv = fmaxf(acc[r] + bb, 0.f);
            hlds[(w * 16 + quad * 4 + r) * H_LD + nt * 16 + p] = bf16r(hv);
        }
    }
    __syncthreads();

    // ---- stage 2: [Q|K|V] = h @ W2 + b ----
    short8 ha0 = *(const short8*)&hlds[(w * 16 + p) * H_LD + quad * 8];
    short8 ha1 = *(const short8*)&hlds[(w * 16 + p) * H_LD + 32 + quad * 8];
    int node_r = mbase + quad * 4;
    #pragma unroll
    for (int nt = 0; nt < 12; ++nt) {
        f4v acc = {0.f, 0.f, 0.f, 0.f};
        short8 b0 = *(const short8*)&w2t[(nt * 16 + p) * W2T_LD + quad * 8];
        short8 b1 = *(const short8*)&w2t[(nt * 16 + p) * W2T_LD + 32 + quad * 8];
        acc = __builtin_amdgcn_mfma_f32_16x16x32_bf16(ha0, b0, acc, 0, 0, 0);
        acc = __builtin_amdgcn_mfma_f32_16x16x32_bf16(ha1, b1, acc, 0, 0, 0);
        int col = nt * 16 + p;
        #pragma unroll
        for (int r = 0; r < 4; ++r) {
            int node = node_r + r;
            if (node >= N) continue;
            float v = acc[r];
            if (col < 64) {
                v += bq[col];
                Q[(size_t)node * 64 + col] = (v > 0.f) ? (1.f + v) : __expf(v);
            } else if (col < 128) {
                int c = col - 64;
                v += bk[c];
                float kv = (v > 0.f) ? (1.f + v) : __expf(v);
                K0[(size_t)node * 64 + c] = f32_to_fp8(kv);
            } else {
                int c = col - 128;
                v += bv[c];
                Vh[(size_t)node * 64 + c] = (_Float16)v;
            }
        }
    }
}

// ---------------- hop 1: rec1 = A (K ⊗ V) packed fp4+scale+K ----------------
// also writes the hop-0 term: hidden = V*temp[:,0] + gamma1*(...)
__global__ __launch_bounds__(256) void hop1_all(
    const float* __restrict__ Q, const unsigned char* __restrict__ K0,
    const _Float16* __restrict__ Vh,
    const int* __restrict__ offsets, const int* __restrict__ csr,
    const float* __restrict__ temp, const float* __restrict__ hopwise,
    uint3* __restrict__ rec1, float* __restrict__ hidden, int N)
{
    int lane = threadIdx.x & 63;
    int node = blockIdx.x * 4 + (threadIdx.x >> 6);
    if (node >= N) return;
    int h = lane >> 4;
    float gh = gamma_for(temp, hopwise, h, 1);
    // hoisted independent loads: latency hides under the gather loop
    float h0 = (float)Vh[(size_t)node * 64 + lane] * temp[h * 4];
    float qd = Q[(size_t)node * 64 + lane];
    h2 u16[8];
    #pragma unroll
    for (int j = 0; j < 8; ++j) u16[j] = h2{(_Float16)0.f, (_Float16)0.f};
    float kacc = 0.f;
    // scalarized loop bounds: loop control + csr + row bases on SALU/SMEM
    int beg = uni(offsets[node]), end = uni(offsets[node + 1]);
    int t = beg;
    for (; t + 3 < end; t += 4) {
        int s0 = uni(csr[t]),     s1 = uni(csr[t + 1]);
        int s2 = uni(csr[t + 2]), s3 = uni(csr[t + 3]);
        const uint4* v0p = (const uint4*)(Vh + (size_t)s0 * 64 + h * 16);
        const uint4* v1p = (const uint4*)(Vh + (size_t)s1 * 64 + h * 16);
        const uint4* v2p = (const uint4*)(Vh + (size_t)s2 * 64 + h * 16);
        const uint4* v3p = (const uint4*)(Vh + (size_t)s3 * 64 + h * 16);
        uint4 a00 = v0p[0], a01 = v0p[1];
        uint4 a10 = v1p[0], a11 = v1p[1];
        uint4 a20 = v2p[0], a21 = v2p[1];
        uint4 a30 = v3p[0], a31 = v3p[1];
        unsigned char k0 = K0[(size_t)s0 * 64 + lane];
        unsigned char k1 = K0[(size_t)s1 * 64 + lane];
        unsigned char k2 = K0[(size_t)s2 * 64 + lane];
        unsigned char k3 = K0[(size_t)s3 * 64 + lane];
        acc_edge1(u16, kacc, a00, a01, k0);
        acc_edge1(u16, kacc, a10, a11, k1);
        acc_edge1(u16, kacc, a20, a21, k2);
        acc_edge1(u16, kacc, a30, a31, k3);
    }
    for (; t < end; ++t) {
        int s = uni(csr[t]);
        const uint4* vp = (const uint4*)(Vh + (size_t)s * 64 + h * 16);
        uint4 a0 = vp[0], a1 = vp[1];
        unsigned char kk = K0[(size_t)s * 64 + lane];
        acc_edge1(u16, kacc, a0, a1, kk);
    }
    float u[16];
    #pragma unroll
    for (int j = 0; j < 8; ++j) { u[2 * j] = (float)u16[j].x; u[2 * j + 1] = (float)u16[j].y; }
    store_m_row(rec1, node, lane, u, kacc);
    #pragma unroll
    for (int j = 0; j < 16; ++j) u[j] *= qd;
    reduce_scatter16(u, lane & 15);
    float g = gh / den16(qd, kacc);
    hidden[(size_t)node * 64 + lane] = h0 + g * u[0];
}

// ---------------- hops 2/3: packed 12B record gather ----------------
// STORE=true : hop 2 — store rec2, accumulate into hidden
// STORE=false: hop 3 — no store; fuse the output projection (out = hidden@Wo+bo)
template<bool STORE>
__global__ __launch_bounds__(256) void hop23_all(
    const float* __restrict__ Q, const uint3* __restrict__ recp,
    const int* __restrict__ offsets, const int* __restrict__ csr,
    const float* __restrict__ temp, const float* __restrict__ hopwise,
    uint3* __restrict__ recn, float* __restrict__ hidden,
    const float* __restrict__ Wo, const float* __restrict__ bo,
    float* __restrict__ out, int N, int hop)
{
    int lane = threadIdx.x & 63;
    int node = blockIdx.x * 4 + (threadIdx.x >> 6);
    if (node >= N) return;
    float gh = gamma_for(temp, hopwise, lane >> 4, hop);
    // hoisted independent epilogue loads — latency hides under the gather
    float qd  = Q[(size_t)node * 64 + lane];
    float hv0 = STORE ? 0.f : hidden[(size_t)node * 64 + lane];
    f2 u2[8];
    #pragma unroll
    for (int j = 0; j < 8; ++j) u2[j] = f2{0.f, 0.f};
    float kacc = 0.f;
    // scalarized loop bounds + csr + row bases (wave-uniform) → SALU/SMEM
    int beg = uni(offsets[node]), end = uni(offsets[node + 1]);
    int t = beg;
    // 4-edge batches, ONE dwordx3 load per edge per lane (merged M+SK record)
    for (; t + 3 < end; t += 4) {
        int s0 = uni(csr[t]),     s1 = uni(csr[t + 1]);
        int s2 = uni(csr[t + 2]), s3 = uni(csr[t + 3]);
        uint3 w0 = recp[(size_t)s0 * 64 + lane];
        uint3 w1 = recp[(size_t)s1 * 64 + lane];
        uint3 w2 = recp[(size_t)s2 * 64 + lane];
        uint3 w3 = recp[(size_t)s3 * 64 + lane];
        acc_edge23(u2, kacc, w0);
        acc_edge23(u2, kacc, w1);
        acc_edge23(u2, kacc, w2);
        acc_edge23(u2, kacc, w3);
    }
    for (; t < end; ++t) {
        int sn = uni(csr[t]);
        uint3 w = recp[(size_t)sn * 64 + lane];
        acc_edge23(u2, kacc, w);
    }
    float u[16];
    #pragma unroll
    for (int j = 0; j < 8; ++j) { u[2 * j] = u2[j].x; u[2 * j + 1] = u2[j].y; }
    if constexpr (STORE) store_m_row(recn, node, lane, u, kacc);
    #pragma unroll
    for (int j = 0; j < 16; ++j) u[j] *= qd;
    reduce_scatter16(u, lane & 15);
    float g = gh / den16(qd, kacc);
    if constexpr (STORE) {
        hidden[(size_t)node * 64 + lane] += g * u[0];
    } else {
        // fused output projection: each lane holds one hidden element of the row.
        // Wo row loaded AFTER the gather loop — keeps it out of the hot-loop
        // register budget (round-1 lesson: 16 live VGPRs there cost occupancy).
        float wrow[16];
        {
            const f4v* wp = (const f4v*)(Wo + (size_t)lane * 16);
            f4v a = wp[0], b = wp[1], c = wp[2], d = wp[3];
            wrow[0]=a[0]; wrow[1]=a[1]; wrow[2]=a[2]; wrow[3]=a[3];
            wrow[4]=b[0]; wrow[5]=b[1]; wrow[6]=b[2]; wrow[7]=b[3];
            wrow[8]=c[0]; wrow[9]=c[1]; wrow[10]=c[2]; wrow[11]=c[3];
            wrow[12]=d[0]; wrow[13]=d[1]; wrow[14]=d[2]; wrow[15]=d[3];
        }
        float hv = hv0 + g * u[0];
        float o[16];
        #pragma unroll
        for (int j = 0; j < 16; ++j) o[j] = hv * wrow[j];
        reduce_scatter16(o, lane & 15);          // per-quad partials, col = lane&15
        float r = o[0];
        r += __shfl_xor(r, 16, 64);              // sum the 4 quads
        r += __shfl_xor(r, 32, 64);
        if (lane < 16) out[(size_t)node * 16 + lane] = r + bo[lane];
    }
}

extern "C" void kernel_launch(void* const* d_in, const int* in_sizes, int n_in,
                              void* d_out, int out_size, void* d_ws, size_t ws_size,
                              hipStream_t stream) {
    const float* x       = (const float*)d_in[0];
    const int*   ei      = (const int*)  d_in[1];
    const float* Wi      = (const float*)d_in[2];
    const float* bi      = (const float*)d_in[3];
    const float* Wq      = (const float*)d_in[4];
    const float* bq      = (const float*)d_in[5];
    const float* Wk      = (const float*)d_in[6];
    const float* bk      = (const float*)d_in[7];
    const float* Wv      = (const float*)d_in[8];
    const float* bv      = (const float*)d_in[9];
    const float* Wo      = (const float*)d_in[10];
    const float* bo      = (const float*)d_in[11];
    const float* hopwise = (const float*)d_in[12];
    const float* temp    = (const float*)d_in[13];

    const int N = in_sizes[0] / F_IN;
    const int E = in_sizes[1] / 2;

    char* ws = (char*)d_ws;
    size_t off = 0;
    auto take = [&](size_t bytes) -> char* {
        char* p = ws + off;
        off += (bytes + 255) & ~(size_t)255;
        return p;
    };
    float*          Q      = (float*)take((size_t)N * 64 * 4);
    _Float16*       Vh     = (_Float16*)take((size_t)N * 64 * 2);
    float*          hidden = (float*)take((size_t)N * 64 * 4);
    unsigned char*  K0     = (unsigned char*)take((size_t)N * 64);
    int*            degcur = (int*)take((size_t)2 * N * 4);   // deg | cursor
    int*            offs   = (int*)take((size_t)(N + 1) * 4);
    int*            csr    = (int*)take((size_t)E * 4);
    int             nb     = (N + 4095) / 4096;
    int*            bsum   = (int*)take((size_t)nb * 4);
    uint3*          rec1   = (uint3*)take((size_t)N * 64 * 12);
    uint3*          rec2   = (uint3*)take((size_t)N * 64 * 12);

    int* deg    = degcur;
    int* cursor = degcur + N;

    hipMemsetAsync(degcur, 0, (size_t)2 * N * 4, stream);

    int eb = (E + 255) / 256;
    int qb = (N + 63) / 64;
    // fused: qkv (qb blocks) + degree count (eb blocks)
    qkv_count<<<qb + eb, 256, 0, stream>>>(x, Wi, bi, Wq, bq, Wk, bk, Wv, bv,
                                           Q, K0, Vh,
                                           ei, deg, E, qb, N);
    scan_a<<<nb, 1024, 0, stream>>>(deg, offs, bsum, N);
    scan_c<<<(N + 255) / 256, 256, 0, stream>>>(offs, bsum, nb, N);
    scatter_kernel<<<eb, 256, 0, stream>>>(ei, offs, cursor, csr, E);

    int nb4 = (N + 3) / 4;
    hop1_all<<<nb4, 256, 0, stream>>>(Q, K0, Vh, offs, csr, temp, hopwise,
                                      rec1, hidden, N);
    hop23_all<true ><<<nb4, 256, 0, stream>>>(Q, rec1, offs, csr, temp, hopwise,
                                              rec2, hidden,
                                              (const float*)nullptr, (const float*)nullptr,
                                              (float*)nullptr, N, 2);
    hop23_all<false><<<nb4, 256, 0, stream>>>(Q, rec2, offs, csr, temp, hopwise,
                                              (uint3*)nullptr, hidden,
                                              Wo, bo, (float*)d_out, N, 3);
}

// Round 7
// 288.723 us; speedup vs baseline: 1.0254x; 1.0254x over previous
//
#include <hip/hip_runtime.h>
#include <math.h>

#define F_IN 128
#define HID  64
#define NH   4
#define DD   16
#define CC   16
#define CSTE 1e-5f

typedef _Float16 h2     __attribute__((ext_vector_type(2)));
typedef float    f2     __attribute__((ext_vector_type(2)));
typedef short    short8 __attribute__((ext_vector_type(8)));
typedef float    f4v    __attribute__((ext_vector_type(4)));

// LDS strides (elements) — padded so b128 frag reads are ≤2-way bank conflicts
#define WIT_LD 136
#define W2T_LD 72
#define H_LD   72

__device__ __forceinline__ unsigned short bf16r(float f) {
    unsigned int u = __builtin_bit_cast(unsigned int, f);
    unsigned int r = (u + 0x7FFFu + ((u >> 16) & 1u)) >> 16;
    return (unsigned short)r;
}

// wave-uniform hint: value is identical across the wave; moves it to SGPR so
// loop control / index loads / base addresses go to the SALU+SMEM pipes
// (parallel to VALU) instead of 64-lane vector address math.
__device__ __forceinline__ int uni(int v) {
    return __builtin_amdgcn_readfirstlane(v);
}

// ---------------- fp8 scalar helpers (OCP e4m3 via hw cvt) ----------------
__device__ __forceinline__ float fp8_to_f32(unsigned int b) {
    f2 v = __builtin_amdgcn_cvt_pk_f32_fp8((int)b, false);
    return v.x;
}
__device__ __forceinline__ f2 fp8x2_to_f32(unsigned int w) {   // bytes 0,1 of w
    return __builtin_amdgcn_cvt_pk_f32_fp8((int)w, false);
}
__device__ __forceinline__ f2 fp8x2_to_f32_hi(unsigned int w) { // bytes 2,3 of w
    return __builtin_amdgcn_cvt_pk_f32_fp8((int)w, true);
}
__device__ __forceinline__ unsigned char f32_to_fp8(float f) {
    int w = __builtin_amdgcn_cvt_pk_fp8_f32(f, f, 0, false);
    return (unsigned char)(w & 0xff);
}

// ---------------- fp4 e2m1 helpers ----------------
__device__ __forceinline__ float fp4_dec1(unsigned int n) {
    unsigned int e = (n >> 1) & 3u, m = n & 1u;
    float mag = (e == 0) ? 0.5f * (float)m
                         : (float)(1u << (e - 1)) * (1.0f + 0.5f * (float)m);
    return (n & 8u) ? -mag : mag;
}
__device__ __forceinline__ unsigned int fp4_enc1(float f) {
    unsigned int s = (f < 0.f) ? 8u : 0u;
    float a = fabsf(f);
    unsigned int m;
    if      (a < 0.25f) m = 0u;
    else if (a < 0.75f) m = 1u;
    else if (a < 1.25f) m = 2u;
    else if (a < 1.75f) m = 3u;
    else if (a < 2.5f)  m = 4u;
    else if (a < 3.5f)  m = 5u;
    else if (a < 5.0f)  m = 6u;
    else                m = 7u;
    return s | m;
}

#if __has_builtin(__builtin_amdgcn_cvt_scalef32_pk_f32_fp4) && __has_builtin(__builtin_amdgcn_cvt_scalef32_pk_fp4_f32)
#define HAS_FP4 1
#endif

// decode 16 fp4 nibbles into 8 packed f2 pairs (natural order)
__device__ __forceinline__ void fp4x16_dec2(uint2 w, f2* v) {
#ifdef HAS_FP4
    v[0] = __builtin_amdgcn_cvt_scalef32_pk_f32_fp4(w.x, 1.0f, 0);
    v[1] = __builtin_amdgcn_cvt_scalef32_pk_f32_fp4(w.x, 1.0f, 1);
    v[2] = __builtin_amdgcn_cvt_scalef32_pk_f32_fp4(w.x, 1.0f, 2);
    v[3] = __builtin_amdgcn_cvt_scalef32_pk_f32_fp4(w.x, 1.0f, 3);
    v[4] = __builtin_amdgcn_cvt_scalef32_pk_f32_fp4(w.y, 1.0f, 0);
    v[5] = __builtin_amdgcn_cvt_scalef32_pk_f32_fp4(w.y, 1.0f, 1);
    v[6] = __builtin_amdgcn_cvt_scalef32_pk_f32_fp4(w.y, 1.0f, 2);
    v[7] = __builtin_amdgcn_cvt_scalef32_pk_f32_fp4(w.y, 1.0f, 3);
#else
    #pragma unroll
    for (int j = 0; j < 4; ++j) {
        v[j].x     = fp4_dec1((w.x >> (8 * j)) & 0xFu);
        v[j].y     = fp4_dec1((w.x >> (8 * j + 4)) & 0xFu);
        v[4 + j].x = fp4_dec1((w.y >> (8 * j)) & 0xFu);
        v[4 + j].y = fp4_dec1((w.y >> (8 * j + 4)) & 0xFu);
    }
#endif
}

__device__ __forceinline__ uint2 fp4x16_enc(const float* v) {
#ifdef HAS_FP4
    unsigned int a = 0u, b = 0u;
    a = __builtin_amdgcn_cvt_scalef32_pk_fp4_f32(a, v[0],  v[1],  1.0f, 0);
    a = __builtin_amdgcn_cvt_scalef32_pk_fp4_f32(a, v[2],  v[3],  1.0f, 1);
    a = __builtin_amdgcn_cvt_scalef32_pk_fp4_f32(a, v[4],  v[5],  1.0f, 2);
    a = __builtin_amdgcn_cvt_scalef32_pk_fp4_f32(a, v[6],  v[7],  1.0f, 3);
    b = __builtin_amdgcn_cvt_scalef32_pk_fp4_f32(b, v[8],  v[9],  1.0f, 0);
    b = __builtin_amdgcn_cvt_scalef32_pk_fp4_f32(b, v[10], v[11], 1.0f, 1);
    b = __builtin_amdgcn_cvt_scalef32_pk_fp4_f32(b, v[12], v[13], 1.0f, 2);
    b = __builtin_amdgcn_cvt_scalef32_pk_fp4_f32(b, v[14], v[15], 1.0f, 3);
    return {a, b};
#else
    unsigned int a = 0u, b = 0u;
    #pragma unroll
    for (int j = 0; j < 8; ++j) {
        a |= fp4_enc1(v[j])     << (4 * j);
        b |= fp4_enc1(v[8 + j]) << (4 * j);
    }
    return {a, b};
#endif
}

// store one M row: per-row fp8 scale (s8), fp4 payload, K packed with scale
__device__ __forceinline__ void store_m_row(
    uint2* __restrict__ Mout, unsigned short* __restrict__ SKout,
    int node, int lane, const float* u, float kacc)
{
    float rm = 0.f;
    #pragma unroll
    for (int j = 0; j < 16; ++j) rm = fmaxf(rm, fabsf(u[j]));
    unsigned char s8 = f32_to_fp8(rm * (1.0f / 6.0f));
    float se = fp8_to_f32((unsigned int)s8);
    float invs = (se > 0.f) ? (1.0f / se) : 0.f;
    float tq[16];
    #pragma unroll
    for (int j = 0; j < 16; ++j) tq[j] = u[j] * invs;
    Mout[(size_t)node * 64 + lane] = fp4x16_enc(tq);
    SKout[(size_t)node * 64 + lane] =
        (unsigned short)((unsigned short)s8 | ((unsigned short)f32_to_fp8(kacc) << 8));
}

// per-hop gamma (hop>=1): hopwise[hop] * softmax_over_heads(temp[:,hop])[h]
__device__ __forceinline__ float gamma_for(const float* __restrict__ temp,
                                           const float* __restrict__ hopwise,
                                           int h, int hop) {
    float t0 = temp[0 * 4 + hop], t1 = temp[1 * 4 + hop];
    float t2 = temp[2 * 4 + hop], t3 = temp[3 * 4 + hop];
    float mx = fmaxf(fmaxf(t0, t1), fmaxf(t2, t3));
    float e0 = __expf(t0 - mx), e1 = __expf(t1 - mx);
    float e2 = __expf(t2 - mx), e3 = __expf(t3 - mx);
    float ssum = e0 + e1 + e2 + e3;
    float eh = (h == 0) ? e0 : (h == 1) ? e1 : (h == 2) ? e2 : e3;
    return hopwise[hop] * eh / ssum;
}

// reduce-scatter over the 16 lanes of a head: u[j] holds column j (natural);
// afterwards lane p holds, in u[0], the group sum for column p.
__device__ __forceinline__ void reduce_scatter16(float* u, int p) {
    #pragma unroll
    for (int k = 0; k < 4; ++k) {
        const int m = 1 << k;
        bool bit = (p >> k) & 1;
        const int n = 8 >> k;
        #pragma unroll
        for (int j = 0; j < n; ++j) {
            float give = bit ? u[2 * j]     : u[2 * j + 1];
            float keep = bit ? u[2 * j + 1] : u[2 * j];
            float got  = __shfl_xor(give, m, 64);
            u[j] = keep + got;
        }
    }
}

// den = sum over the 16-lane group of qd*kacc, plus CST
__device__ __forceinline__ float den16(float qd, float kacc) {
    float kq = qd * kacc;
    kq += __shfl_xor(kq, 1, 64);
    kq += __shfl_xor(kq, 2, 64);
    kq += __shfl_xor(kq, 4, 64);
    kq += __shfl_xor(kq, 8, 64);
    return kq + CSTE;
}

// per-edge accumulate for hops 2/3: u2 += scale * dec(w); kacc += K
__device__ __forceinline__ void acc_edge23(f2* u2, float& kacc,
                                           uint2 w, unsigned int skraw) {
    f2 sk = fp8x2_to_f32(skraw);
    kacc += sk.y;
    f2 v[8];
    fp4x16_dec2(w, v);
    f2 s = {sk.x, sk.x};
    #pragma unroll
    for (int j = 0; j < 8; ++j) u2[j] = s * v[j] + u2[j];
}

// per-edge accumulate for hop 1 from a packed VK record: 16 fp8 V values
// (broadcast uint4 per head) scaled by this lane's fp8 K.
__device__ __forceinline__ void acc_edge1(f2* u2, float& kacc,
                                          uint4 vw, unsigned int kraw) {
    float kk = fp8_to_f32(kraw);
    kacc += kk;
    f2 v[8];
    v[0] = fp8x2_to_f32(vw.x);  v[1] = fp8x2_to_f32_hi(vw.x);
    v[2] = fp8x2_to_f32(vw.y);  v[3] = fp8x2_to_f32_hi(vw.y);
    v[4] = fp8x2_to_f32(vw.z);  v[5] = fp8x2_to_f32_hi(vw.z);
    v[6] = fp8x2_to_f32(vw.w);  v[7] = fp8x2_to_f32_hi(vw.w);
    f2 s = {kk, kk};
    #pragma unroll
    for (int j = 0; j < 8; ++j) u2[j] = s * v[j] + u2[j];
}

// ---------------- CSR scan ----------------
__global__ __launch_bounds__(1024) void scan_a(const int* __restrict__ deg,
                                               int* __restrict__ offsets,
                                               int* __restrict__ bsum, int N) {
    __shared__ int wsum[16], woff[16];
    int lane = threadIdx.x & 63, w = threadIdx.x >> 6;
    int i0 = blockIdx.x * 4096 + (int)threadIdx.x * 4;
    int d0 = (i0 + 0 < N) ? deg[i0 + 0] : 0;
    int d1 = (i0 + 1 < N) ? deg[i0 + 1] : 0;
    int d2 = (i0 + 2 < N) ? deg[i0 + 2] : 0;
    int d3 = (i0 + 3 < N) ? deg[i0 + 3] : 0;
    int tsum = d0 + d1 + d2 + d3;
    int incl = tsum;
    #pragma unroll
    for (int m = 1; m < 64; m <<= 1) {
        int t = __shfl_up(incl, m, 64);
        if (lane >= m) incl += t;
    }
    if (lane == 63) wsum[w] = incl;
    __syncthreads();
    if (threadIdx.x == 0) {
        int r = 0;
        for (int k = 0; k < 16; ++k) { int t = wsum[k]; woff[k] = r; r += t; }
        bsum[blockIdx.x] = r;
    }
    __syncthreads();
    int excl = woff[w] + incl - tsum;
    if (i0 + 0 < N) offsets[i0 + 0] = excl;
    if (i0 + 1 < N) offsets[i0 + 1] = excl + d0;
    if (i0 + 2 < N) offsets[i0 + 2] = excl + d0 + d1;
    if (i0 + 3 < N) offsets[i0 + 3] = excl + d0 + d1 + d2;
}

__global__ void scan_c(int* __restrict__ offsets, const int* __restrict__ bsum,
                       int nb, int N) {
    int i = blockIdx.x * blockDim.x + threadIdx.x;
    if (i < N) {
        int bkt = i >> 12;
        int base = 0;
        for (int b = 0; b < bkt; ++b) base += bsum[b];
        offsets[i] += base;
    }
    if (i == 0) {
        int tot = 0;
        for (int b = 0; b < nb; ++b) tot += bsum[b];
        offsets[N] = tot;
    }
}

__global__ void scatter_kernel(const int* __restrict__ ei, const int* __restrict__ offsets,
                               int* __restrict__ cursor, int* __restrict__ csr, int E) {
    int e = blockIdx.x * blockDim.x + threadIdx.x;
    if (e < E) {
        int src = ei[e];
        int dst = ei[E + e];
        int pos = atomicAdd(&cursor[dst], 1);
        csr[offsets[dst] + pos] = src;
    }
}

// ---------------- fused MFMA QKV + edge counting ----------------
// blocks [0, qb): qkv (64 nodes/block); blocks [qb, qb+eb): degree count
// VKq[node] = 128B packed record: bytes [0..63] V fp8 (natural cols), [64..127] K fp8.
__global__ __launch_bounds__(256) void qkv_count(
    const float* __restrict__ x,
    const float* __restrict__ Wi, const float* __restrict__ bi,
    const float* __restrict__ Wq, const float* __restrict__ bq,
    const float* __restrict__ Wk, const float* __restrict__ bk,
    const float* __restrict__ Wv, const float* __restrict__ bv,
    float* __restrict__ Q, unsigned char* __restrict__ VKq,
    _Float16* __restrict__ Vh,
    const int* __restrict__ ei, int* __restrict__ deg,
    int E, int qb, int N)
{
    __shared__ unsigned short wit[64 * WIT_LD];
    __shared__ unsigned short w2t[192 * W2T_LD];
    __shared__ unsigned short hlds[64 * H_LD];
    if ((int)blockIdx.x >= qb) {
        int e = ((int)blockIdx.x - qb) * 256 + (int)threadIdx.x;
        if (e < E) atomicAdd(&deg[ei[E + e]], 1);   // dst = ei[1][e]
        return;
    }
    int t = threadIdx.x;
    #pragma unroll
    for (int i = 0; i < 32; ++i) {
        int g = t + i * 256;                       // 8192 = 128*64
        wit[(g & 63) * WIT_LD + (g >> 6)] = bf16r(Wi[g]);
    }
    #pragma unroll
    for (int i = 0; i < 16; ++i) {
        int g = t + i * 256;                       // 4096 = 64*64
        int k = g >> 6, n = g & 63;
        w2t[(n      ) * W2T_LD + k] = bf16r(Wq[g]);
        w2t[(n +  64) * W2T_LD + k] = bf16r(Wk[g]);
        w2t[(n + 128) * W2T_LD + k] = bf16r(Wv[g]);
    }
    __syncthreads();

    int lane = t & 63, w = t >> 6;
    int p = lane & 15, quad = lane >> 4;
    int mbase = blockIdx.x * 64 + w * 16;

    // ---- stage 1: h = relu(x@Wi + bi) ----
    short8 afrag[4];
    {
        int node = mbase + p;
        if (node >= N) node = N - 1;               // clamped read; stores guarded
        const float* xr = x + (size_t)node * F_IN + quad * 8;
        #pragma unroll
        for (int ks = 0; ks < 4; ++ks) {
            float4 a0 = *(const float4*)(xr + ks * 32);
            float4 a1 = *(const float4*)(xr + ks * 32 + 4);
            short8 f;
            f[0] = bf16r(a0.x); f[1] = bf16r(a0.y); f[2] = bf16r(a0.z); f[3] = bf16r(a0.w);
            f[4] = bf16r(a1.x); f[5] = bf16r(a1.y); f[6] = bf16r(a1.z); f[7] = bf16r(a1.w);
            afrag[ks] = f;
        }
    }
    #pragma unroll
    for (int nt = 0; nt < 4; ++nt) {
        f4v acc = {0.f, 0.f, 0.f, 0.f};
        #pragma unroll
        for (int ks = 0; ks < 4; ++ks) {
            short8 b = *(const short8*)&wit[(nt * 16 + p) * WIT_LD + ks * 32 + quad * 8];
            acc = __builtin_amdgcn_mfma_f32_16x16x32_bf16(afrag[ks], b, acc, 0, 0, 0);
        }
        float bb = bi[nt * 16 + p];
        #pragma unroll
        for (int r = 0; r < 4; ++r) {
            float hv = fmaxf(acc[r] + bb, 0.f);
            hlds[(w * 16 + quad * 4 + r) * H_LD + nt * 16 + p] = bf16r(hv);
        }
    }
    __syncthreads();

    // ---- stage 2: [Q|K|V] = h @ W2 + b ----
    short8 ha0 = *(const short8*)&hlds[(w * 16 + p) * H_LD + quad * 8];
    short8 ha1 = *(const short8*)&hlds[(w * 16 + p) * H_LD + 32 + quad * 8];
    int node_r = mbase + quad * 4;
    #pragma unroll
    for (int nt = 0; nt < 12; ++nt) {
        f4v acc = {0.f, 0.f, 0.f, 0.f};
        short8 b0 = *(const short8*)&w2t[(nt * 16 + p) * W2T_LD + quad * 8];
        short8 b1 = *(const short8*)&w2t[(nt * 16 + p) * W2T_LD + 32 + quad * 8];
        acc = __builtin_amdgcn_mfma_f32_16x16x32_bf16(ha0, b0, acc, 0, 0, 0);
        acc = __builtin_amdgcn_mfma_f32_16x16x32_bf16(ha1, b1, acc, 0, 0, 0);
        int col = nt * 16 + p;
        #pragma unroll
        for (int r = 0; r < 4; ++r) {
            int node = node_r + r;
            if (node >= N) continue;
            float v = acc[r];
            if (col < 64) {
                v += bq[col];
                Q[(size_t)node * 64 + col] = (v > 0.f) ? (1.f + v) : __expf(v);
            } else if (col < 128) {
                int c = col - 64;
                v += bk[c];
                float kv = (v > 0.f) ? (1.f + v) : __expf(v);
                VKq[(size_t)node * 128 + 64 + c] = f32_to_fp8(kv);
            } else {
                int c = col - 128;
                v += bv[c];
                Vh[(size_t)node * 64 + c] = (_Float16)v;       // f16 copy for hop-0
                VKq[(size_t)node * 128 + c] = f32_to_fp8(v);   // fp8 copy for gather
            }
        }
    }
}

// M layout: per node 64 uint2 (512 fp4 payload), NATURAL columns:
// lane (h*16+p), nibble j holds M[h][d=p][c=j] / scale.  SK[n][lane] = {scale fp8, K fp8}.

// ---------------- hop 1: M1 = A (K ⊗ V) from packed 128B VK records ----------------
// also writes the hop-0 term: hidden = V*temp[:,0] + gamma1*(...)
__global__ __launch_bounds__(256) void hop1_all(
    const float* __restrict__ Q, const unsigned char* __restrict__ VKq,
    const _Float16* __restrict__ Vh,
    const int* __restrict__ offsets, const int* __restrict__ csr,
    const float* __restrict__ temp, const float* __restrict__ hopwise,
    uint2* __restrict__ M1, unsigned short* __restrict__ SK1,
    float* __restrict__ hidden, int N)
{
    int lane = threadIdx.x & 63;
    int node = blockIdx.x * 4 + (threadIdx.x >> 6);
    if (node >= N) return;
    int h = lane >> 4;
    float gh = gamma_for(temp, hopwise, h, 1);
    // hoisted independent loads: latency hides under the gather loop
    float h0 = (float)Vh[(size_t)node * 64 + lane] * temp[h * 4];
    float qd = Q[(size_t)node * 64 + lane];
    f2 u2[8];
    #pragma unroll
    for (int j = 0; j < 8; ++j) u2[j] = f2{0.f, 0.f};
    float kacc = 0.f;
    // scalarized loop bounds: loop control + csr + row bases on SALU/SMEM
    int beg = uni(offsets[node]), end = uni(offsets[node + 1]);
    int t = beg;
    // 4-edge batches: 2 cache lines per edge (16B broadcast V + 1B K, same 128B rec)
    for (; t + 3 < end; t += 4) {
        int s0 = uni(csr[t]),     s1 = uni(csr[t + 1]);
        int s2 = uni(csr[t + 2]), s3 = uni(csr[t + 3]);
        const unsigned char* b0 = VKq + (size_t)s0 * 128;
        const unsigned char* b1 = VKq + (size_t)s1 * 128;
        const unsigned char* b2 = VKq + (size_t)s2 * 128;
        const unsigned char* b3 = VKq + (size_t)s3 * 128;
        uint4 v0 = *(const uint4*)(b0 + h * 16);
        uint4 v1 = *(const uint4*)(b1 + h * 16);
        uint4 v2 = *(const uint4*)(b2 + h * 16);
        uint4 v3 = *(const uint4*)(b3 + h * 16);
        unsigned char k0 = b0[64 + lane];
        unsigned char k1 = b1[64 + lane];
        unsigned char k2 = b2[64 + lane];
        unsigned char k3 = b3[64 + lane];
        acc_edge1(u2, kacc, v0, k0);
        acc_edge1(u2, kacc, v1, k1);
        acc_edge1(u2, kacc, v2, k2);
        acc_edge1(u2, kacc, v3, k3);
    }
    for (; t < end; ++t) {
        int s = uni(csr[t]);
        const unsigned char* b = VKq + (size_t)s * 128;
        uint4 vw = *(const uint4*)(b + h * 16);
        unsigned char kk = b[64 + lane];
        acc_edge1(u2, kacc, vw, kk);
    }
    float u[16];
    #pragma unroll
    for (int j = 0; j < 8; ++j) { u[2 * j] = u2[j].x; u[2 * j + 1] = u2[j].y; }
    store_m_row(M1, SK1, node, lane, u, kacc);
    #pragma unroll
    for (int j = 0; j < 16; ++j) u[j] *= qd;
    reduce_scatter16(u, lane & 15);
    float g = gh / den16(qd, kacc);
    hidden[(size_t)node * 64 + lane] = h0 + g * u[0];
}

// ---------------- hops 2/3: fp4 M gather (r3 split-array layout, proven best) ----------------
// STORE=true : hop 2 — store M2/SK2, accumulate into hidden
// STORE=false: hop 3 — no M store; fuse the output projection (out = hidden@Wo+bo)
template<bool STORE>
__global__ __launch_bounds__(256) void hop23_all(
    const float* __restrict__ Q, const uint2* __restrict__ Mprev,
    const unsigned short* __restrict__ SKprev,
    const int* __restrict__ offsets, const int* __restrict__ csr,
    const float* __restrict__ temp, const float* __restrict__ hopwise,
    uint2* __restrict__ Mnext, unsigned short* __restrict__ SKnext,
    float* __restrict__ hidden,
    const float* __restrict__ Wo, const float* __restrict__ bo,
    float* __restrict__ out, int N, int hop)
{
    int lane = threadIdx.x & 63;
    int node = blockIdx.x * 4 + (threadIdx.x >> 6);
    if (node >= N) return;
    float gh = gamma_for(temp, hopwise, lane >> 4, hop);
    // hoisted independent epilogue loads — latency hides under the gather
    float qd  = Q[(size_t)node * 64 + lane];
    float hv0 = STORE ? 0.f : hidden[(size_t)node * 64 + lane];
    f2 u2[8];
    #pragma unroll
    for (int j = 0; j < 8; ++j) u2[j] = f2{0.f, 0.f};
    float kacc = 0.f;
    // scalarized loop bounds + csr + row bases (wave-uniform) → SALU/SMEM
    int beg = uni(offsets[node]), end = uni(offsets[node + 1]);
    int t = beg;
    // 4-edge batches (round-3 best: 8 loads in flight, VGPR stays ~28)
    for (; t + 3 < end; t += 4) {
        int s0 = uni(csr[t]),     s1 = uni(csr[t + 1]);
        int s2 = uni(csr[t + 2]), s3 = uni(csr[t + 3]);
        uint2 w0 = Mprev[(size_t)s0 * 64 + lane];
        uint2 w1 = Mprev[(size_t)s1 * 64 + lane];
        uint2 w2 = Mprev[(size_t)s2 * 64 + lane];
        uint2 w3 = Mprev[(size_t)s3 * 64 + lane];
        unsigned short k0 = SKprev[(size_t)s0 * 64 + lane];
        unsigned short k1 = SKprev[(size_t)s1 * 64 + lane];
        unsigned short k2 = SKprev[(size_t)s2 * 64 + lane];
        unsigned short k3 = SKprev[(size_t)s3 * 64 + lane];
        acc_edge23(u2, kacc, w0, k0);
        acc_edge23(u2, kacc, w1, k1);
        acc_edge23(u2, kacc, w2, k2);
        acc_edge23(u2, kacc, w3, k3);
    }
    for (; t < end; ++t) {
        int sn = uni(csr[t]);
        uint2 w = Mprev[(size_t)sn * 64 + lane];
        unsigned short skr = SKprev[(size_t)sn * 64 + lane];
        acc_edge23(u2, kacc, w, skr);
    }
    float u[16];
    #pragma unroll
    for (int j = 0; j < 8; ++j) { u[2 * j] = u2[j].x; u[2 * j + 1] = u2[j].y; }
    if constexpr (STORE) store_m_row(Mnext, SKnext, node, lane, u, kacc);
    #pragma unroll
    for (int j = 0; j < 16; ++j) u[j] *= qd;
    reduce_scatter16(u, lane & 15);
    float g = gh / den16(qd, kacc);
    if constexpr (STORE) {
        hidden[(size_t)node * 64 + lane] += g * u[0];
    } else {
        // fused output projection: each lane holds one hidden element of the row.
        // Wo row loaded AFTER the gather loop — keeps it out of the hot-loop
        // register budget (round-1 lesson: 16 live VGPRs there cost occupancy).
        float wrow[16];
        {
            const f4v* wp = (const f4v*)(Wo + (size_t)lane * 16);
            f4v a = wp[0], b = wp[1], c = wp[2], d = wp[3];
            wrow[0]=a[0]; wrow[1]=a[1]; wrow[2]=a[2]; wrow[3]=a[3];
            wrow[4]=b[0]; wrow[5]=b[1]; wrow[6]=b[2]; wrow[7]=b[3];
            wrow[8]=c[0]; wrow[9]=c[1]; wrow[10]=c[2]; wrow[11]=c[3];
            wrow[12]=d[0]; wrow[13]=d[1]; wrow[14]=d[2]; wrow[15]=d[3];
        }
        float hv = hv0 + g * u[0];
        float o[16];
        #pragma unroll
        for (int j = 0; j < 16; ++j) o[j] = hv * wrow[j];
        reduce_scatter16(o, lane & 15);          // per-quad partials, col = lane&15
        float r = o[0];
        r += __shfl_xor(r, 16, 64);              // sum the 4 quads
        r += __shfl_xor(r, 32, 64);
        if (lane < 16) out[(size_t)node * 16 + lane] = r + bo[lane];
    }
}

extern "C" void kernel_launch(void* const* d_in, const int* in_sizes, int n_in,
                              void* d_out, int out_size, void* d_ws, size_t ws_size,
                              hipStream_t stream) {
    const float* x       = (const float*)d_in[0];
    const int*   ei      = (const int*)  d_in[1];
    const float* Wi      = (const float*)d_in[2];
    const float* bi      = (const float*)d_in[3];
    const float* Wq      = (const float*)d_in[4];
    const float* bq      = (const float*)d_in[5];
    const float* Wk      = (const float*)d_in[6];
    const float* bk      = (const float*)d_in[7];
    const float* Wv      = (const float*)d_in[8];
    const float* bv      = (const float*)d_in[9];
    const float* Wo      = (const float*)d_in[10];
    const float* bo      = (const float*)d_in[11];
    const float* hopwise = (const float*)d_in[12];
    const float* temp    = (const float*)d_in[13];

    const int N = in_sizes[0] / F_IN;
    const int E = in_sizes[1] / 2;

    char* ws = (char*)d_ws;
    size_t off = 0;
    auto take = [&](size_t bytes) -> char* {
        char* p = ws + off;
        off += (bytes + 255) & ~(size_t)255;
        return p;
    };
    float*          Q      = (float*)take((size_t)N * 64 * 4);
    _Float16*       Vh     = (_Float16*)take((size_t)N * 64 * 2);
    float*          hidden = (float*)take((size_t)N * 64 * 4);
    unsigned char*  VKq    = (unsigned char*)take((size_t)N * 128);
    unsigned short* SK1    = (unsigned short*)take((size_t)N * 64 * 2);
    unsigned short* SK2    = (unsigned short*)take((size_t)N * 64 * 2);
    int*            degcur = (int*)take((size_t)2 * N * 4);   // deg | cursor
    int*            offs   = (int*)take((size_t)(N + 1) * 4);
    int*            csr    = (int*)take((size_t)E * 4);
    int             nb     = (N + 4095) / 4096;
    int*            bsum   = (int*)take((size_t)nb * 4);
    uint2*          M1     = (uint2*)take((size_t)N * 512);
    uint2*          M2     = (uint2*)take((size_t)N * 512);

    int* deg    = degcur;
    int* cursor = degcur + N;

    hipMemsetAsync(degcur, 0, (size_t)2 * N * 4, stream);

    int eb = (E + 255) / 256;
    int qb = (N + 63) / 64;
    // fused: qkv (qb blocks) + degree count (eb blocks)
    qkv_count<<<qb + eb, 256, 0, stream>>>(x, Wi, bi, Wq, bq, Wk, bk, Wv, bv,
                                           Q, VKq, Vh,
                                           ei, deg, E, qb, N);
    scan_a<<<nb, 1024, 0, stream>>>(deg, offs, bsum, N);
    scan_c<<<(N + 255) / 256, 256, 0, stream>>>(offs, bsum, nb, N);
    scatter_kernel<<<eb, 256, 0, stream>>>(ei, offs, cursor, csr, E);

    int nb4 = (N + 3) / 4;
    hop1_all<<<nb4, 256, 0, stream>>>(Q, VKq, Vh, offs, csr, temp, hopwise,
                                      M1, SK1, hidden, N);
    hop23_all<true ><<<nb4, 256, 0, stream>>>(Q, M1, SK1, offs, csr, temp, hopwise,
                                              M2, SK2, hidden,
                                              (const float*)nullptr, (const float*)nullptr,
                                              (float*)nullptr, N, 2);
    hop23_all<false><<<nb4, 256, 0, stream>>>(Q, M2, SK2, offs, csr, temp, hopwise,
                                              (uint2*)nullptr, (unsigned short*)nullptr,
                                              hidden, Wo, bo, (float*)d_out, N, 3);
}

// Round 8
// 285.036 us; speedup vs baseline: 1.0386x; 1.0129x over previous
//
#include <hip/hip_runtime.h>
#include <math.h>

#define F_IN 128
#define HID  64
#define NH   4
#define DD   16
#define CC   16
#define CSTE 1e-5f

// merged M-row: 640B per node = 512B fp4 payload (64 lanes × 8B) || 128B SK (64 × u16)
#define MROW 640
#define SKOFF 512

typedef _Float16 h2     __attribute__((ext_vector_type(2)));
typedef float    f2     __attribute__((ext_vector_type(2)));
typedef short    short8 __attribute__((ext_vector_type(8)));
typedef float    f4v    __attribute__((ext_vector_type(4)));

// LDS strides (elements) — padded so b128 frag reads are ≤2-way bank conflicts
#define WIT_LD 136
#define W2T_LD 72
#define H_LD   72

__device__ __forceinline__ unsigned short bf16r(float f) {
    unsigned int u = __builtin_bit_cast(unsigned int, f);
    unsigned int r = (u + 0x7FFFu + ((u >> 16) & 1u)) >> 16;
    return (unsigned short)r;
}

// wave-uniform hint: value is identical across the wave; moves it to SGPR so
// loop control / index loads / base addresses go to the SALU+SMEM pipes
// (parallel to VALU) instead of 64-lane vector address math.
__device__ __forceinline__ int uni(int v) {
    return __builtin_amdgcn_readfirstlane(v);
}

// ---------------- fp8 scalar helpers (OCP e4m3 via hw cvt) ----------------
__device__ __forceinline__ float fp8_to_f32(unsigned int b) {
    f2 v = __builtin_amdgcn_cvt_pk_f32_fp8((int)b, false);
    return v.x;
}
__device__ __forceinline__ f2 fp8x2_to_f32(unsigned int w) {   // bytes 0,1 of w
    return __builtin_amdgcn_cvt_pk_f32_fp8((int)w, false);
}
__device__ __forceinline__ f2 fp8x2_to_f32_hi(unsigned int w) { // bytes 2,3 of w
    return __builtin_amdgcn_cvt_pk_f32_fp8((int)w, true);
}
__device__ __forceinline__ unsigned char f32_to_fp8(float f) {
    int w = __builtin_amdgcn_cvt_pk_fp8_f32(f, f, 0, false);
    return (unsigned char)(w & 0xff);
}

// ---------------- fp4 e2m1 helpers ----------------
__device__ __forceinline__ float fp4_dec1(unsigned int n) {
    unsigned int e = (n >> 1) & 3u, m = n & 1u;
    float mag = (e == 0) ? 0.5f * (float)m
                         : (float)(1u << (e - 1)) * (1.0f + 0.5f * (float)m);
    return (n & 8u) ? -mag : mag;
}
__device__ __forceinline__ unsigned int fp4_enc1(float f) {
    unsigned int s = (f < 0.f) ? 8u : 0u;
    float a = fabsf(f);
    unsigned int m;
    if      (a < 0.25f) m = 0u;
    else if (a < 0.75f) m = 1u;
    else if (a < 1.25f) m = 2u;
    else if (a < 1.75f) m = 3u;
    else if (a < 2.5f)  m = 4u;
    else if (a < 3.5f)  m = 5u;
    else if (a < 5.0f)  m = 6u;
    else                m = 7u;
    return s | m;
}

#if __has_builtin(__builtin_amdgcn_cvt_scalef32_pk_f32_fp4) && __has_builtin(__builtin_amdgcn_cvt_scalef32_pk_fp4_f32)
#define HAS_FP4 1
#endif

// decode 16 fp4 nibbles into 8 packed f2 pairs (natural order)
__device__ __forceinline__ void fp4x16_dec2(uint2 w, f2* v) {
#ifdef HAS_FP4
    v[0] = __builtin_amdgcn_cvt_scalef32_pk_f32_fp4(w.x, 1.0f, 0);
    v[1] = __builtin_amdgcn_cvt_scalef32_pk_f32_fp4(w.x, 1.0f, 1);
    v[2] = __builtin_amdgcn_cvt_scalef32_pk_f32_fp4(w.x, 1.0f, 2);
    v[3] = __builtin_amdgcn_cvt_scalef32_pk_f32_fp4(w.x, 1.0f, 3);
    v[4] = __builtin_amdgcn_cvt_scalef32_pk_f32_fp4(w.y, 1.0f, 0);
    v[5] = __builtin_amdgcn_cvt_scalef32_pk_f32_fp4(w.y, 1.0f, 1);
    v[6] = __builtin_amdgcn_cvt_scalef32_pk_f32_fp4(w.y, 1.0f, 2);
    v[7] = __builtin_amdgcn_cvt_scalef32_pk_f32_fp4(w.y, 1.0f, 3);
#else
    #pragma unroll
    for (int j = 0; j < 4; ++j) {
        v[j].x     = fp4_dec1((w.x >> (8 * j)) & 0xFu);
        v[j].y     = fp4_dec1((w.x >> (8 * j + 4)) & 0xFu);
        v[4 + j].x = fp4_dec1((w.y >> (8 * j)) & 0xFu);
        v[4 + j].y = fp4_dec1((w.y >> (8 * j + 4)) & 0xFu);
    }
#endif
}

__device__ __forceinline__ uint2 fp4x16_enc(const float* v) {
#ifdef HAS_FP4
    unsigned int a = 0u, b = 0u;
    a = __builtin_amdgcn_cvt_scalef32_pk_fp4_f32(a, v[0],  v[1],  1.0f, 0);
    a = __builtin_amdgcn_cvt_scalef32_pk_fp4_f32(a, v[2],  v[3],  1.0f, 1);
    a = __builtin_amdgcn_cvt_scalef32_pk_fp4_f32(a, v[4],  v[5],  1.0f, 2);
    a = __builtin_amdgcn_cvt_scalef32_pk_fp4_f32(a, v[6],  v[7],  1.0f, 3);
    b = __builtin_amdgcn_cvt_scalef32_pk_fp4_f32(b, v[8],  v[9],  1.0f, 0);
    b = __builtin_amdgcn_cvt_scalef32_pk_fp4_f32(b, v[10], v[11], 1.0f, 1);
    b = __builtin_amdgcn_cvt_scalef32_pk_fp4_f32(b, v[12], v[13], 1.0f, 2);
    b = __builtin_amdgcn_cvt_scalef32_pk_fp4_f32(b, v[14], v[15], 1.0f, 3);
    return {a, b};
#else
    unsigned int a = 0u, b = 0u;
    #pragma unroll
    for (int j = 0; j < 8; ++j) {
        a |= fp4_enc1(v[j])     << (4 * j);
        b |= fp4_enc1(v[8 + j]) << (4 * j);
    }
    return {a, b};
#endif
}

// store one M row into a merged 640B row: fp4 payload at lane*8, SK at 512+lane*2
__device__ __forceinline__ void store_m_row(
    unsigned char* __restrict__ rowbase, int lane, const float* u, float kacc)
{
    float rm = 0.f;
    #pragma unroll
    for (int j = 0; j < 16; ++j) rm = fmaxf(rm, fabsf(u[j]));
    unsigned char s8 = f32_to_fp8(rm * (1.0f / 6.0f));
    float se = fp8_to_f32((unsigned int)s8);
    float invs = (se > 0.f) ? (1.0f / se) : 0.f;
    float tq[16];
    #pragma unroll
    for (int j = 0; j < 16; ++j) tq[j] = u[j] * invs;
    *(uint2*)(rowbase + lane * 8) = fp4x16_enc(tq);
    *(unsigned short*)(rowbase + SKOFF + lane * 2) =
        (unsigned short)((unsigned short)s8 | ((unsigned short)f32_to_fp8(kacc) << 8));
}

// per-hop gamma (hop>=1): hopwise[hop] * softmax_over_heads(temp[:,hop])[h]
__device__ __forceinline__ float gamma_for(const float* __restrict__ temp,
                                           const float* __restrict__ hopwise,
                                           int h, int hop) {
    float t0 = temp[0 * 4 + hop], t1 = temp[1 * 4 + hop];
    float t2 = temp[2 * 4 + hop], t3 = temp[3 * 4 + hop];
    float mx = fmaxf(fmaxf(t0, t1), fmaxf(t2, t3));
    float e0 = __expf(t0 - mx), e1 = __expf(t1 - mx);
    float e2 = __expf(t2 - mx), e3 = __expf(t3 - mx);
    float ssum = e0 + e1 + e2 + e3;
    float eh = (h == 0) ? e0 : (h == 1) ? e1 : (h == 2) ? e2 : e3;
    return hopwise[hop] * eh / ssum;
}

// reduce-scatter over the 16 lanes of a head: u[j] holds column j (natural);
// afterwards lane p holds, in u[0], the group sum for column p.
__device__ __forceinline__ void reduce_scatter16(float* u, int p) {
    #pragma unroll
    for (int k = 0; k < 4; ++k) {
        const int m = 1 << k;
        bool bit = (p >> k) & 1;
        const int n = 8 >> k;
        #pragma unroll
        for (int j = 0; j < n; ++j) {
            float give = bit ? u[2 * j]     : u[2 * j + 1];
            float keep = bit ? u[2 * j + 1] : u[2 * j];
            float got  = __shfl_xor(give, m, 64);
            u[j] = keep + got;
        }
    }
}

// den = sum over the 16-lane group of qd*kacc, plus CST
__device__ __forceinline__ float den16(float qd, float kacc) {
    float kq = qd * kacc;
    kq += __shfl_xor(kq, 1, 64);
    kq += __shfl_xor(kq, 2, 64);
    kq += __shfl_xor(kq, 4, 64);
    kq += __shfl_xor(kq, 8, 64);
    return kq + CSTE;
}

// per-edge accumulate for hops 2/3: u2 += scale * dec(w); kacc += K
__device__ __forceinline__ void acc_edge23(f2* u2, float& kacc,
                                           uint2 w, unsigned int skraw) {
    f2 sk = fp8x2_to_f32(skraw);
    kacc += sk.y;
    f2 v[8];
    fp4x16_dec2(w, v);
    f2 s = {sk.x, sk.x};
    #pragma unroll
    for (int j = 0; j < 8; ++j) u2[j] = s * v[j] + u2[j];
}

// per-edge accumulate for hop 1 from a packed VK record: 16 fp8 V values
// (broadcast uint4 per head) scaled by this lane's fp8 K.
__device__ __forceinline__ void acc_edge1(f2* u2, float& kacc,
                                          uint4 vw, unsigned int kraw) {
    float kk = fp8_to_f32(kraw);
    kacc += kk;
    f2 v[8];
    v[0] = fp8x2_to_f32(vw.x);  v[1] = fp8x2_to_f32_hi(vw.x);
    v[2] = fp8x2_to_f32(vw.y);  v[3] = fp8x2_to_f32_hi(vw.y);
    v[4] = fp8x2_to_f32(vw.z);  v[5] = fp8x2_to_f32_hi(vw.z);
    v[6] = fp8x2_to_f32(vw.w);  v[7] = fp8x2_to_f32_hi(vw.w);
    f2 s = {kk, kk};
    #pragma unroll
    for (int j = 0; j < 8; ++j) u2[j] = s * v[j] + u2[j];
}

// ---------------- CSR scan ----------------
__global__ __launch_bounds__(1024) void scan_a(const int* __restrict__ deg,
                                               int* __restrict__ offsets,
                                               int* __restrict__ bsum, int N) {
    __shared__ int wsum[16], woff[16];
    int lane = threadIdx.x & 63, w = threadIdx.x >> 6;
    int i0 = blockIdx.x * 4096 + (int)threadIdx.x * 4;
    int d0 = (i0 + 0 < N) ? deg[i0 + 0] : 0;
    int d1 = (i0 + 1 < N) ? deg[i0 + 1] : 0;
    int d2 = (i0 + 2 < N) ? deg[i0 + 2] : 0;
    int d3 = (i0 + 3 < N) ? deg[i0 + 3] : 0;
    int tsum = d0 + d1 + d2 + d3;
    int incl = tsum;
    #pragma unroll
    for (int m = 1; m < 64; m <<= 1) {
        int t = __shfl_up(incl, m, 64);
        if (lane >= m) incl += t;
    }
    if (lane == 63) wsum[w] = incl;
    __syncthreads();
    if (threadIdx.x == 0) {
        int r = 0;
        for (int k = 0; k < 16; ++k) { int t = wsum[k]; woff[k] = r; r += t; }
        bsum[blockIdx.x] = r;
    }
    __syncthreads();
    int excl = woff[w] + incl - tsum;
    if (i0 + 0 < N) offsets[i0 + 0] = excl;
    if (i0 + 1 < N) offsets[i0 + 1] = excl + d0;
    if (i0 + 2 < N) offsets[i0 + 2] = excl + d0 + d1;
    if (i0 + 3 < N) offsets[i0 + 3] = excl + d0 + d1 + d2;
}

__global__ void scan_c(int* __restrict__ offsets, const int* __restrict__ bsum,
                       int nb, int N) {
    int i = blockIdx.x * blockDim.x + threadIdx.x;
    if (i < N) {
        int bkt = i >> 12;
        int base = 0;
        for (int b = 0; b < bkt; ++b) base += bsum[b];
        offsets[i] += base;
    }
    if (i == 0) {
        int tot = 0;
        for (int b = 0; b < nb; ++b) tot += bsum[b];
        offsets[N] = tot;
    }
}

__global__ void scatter_kernel(const int* __restrict__ ei, const int* __restrict__ offsets,
                               int* __restrict__ cursor, int* __restrict__ csr, int E) {
    int e = blockIdx.x * blockDim.x + threadIdx.x;
    if (e < E) {
        int src = ei[e];
        int dst = ei[E + e];
        int pos = atomicAdd(&cursor[dst], 1);
        csr[offsets[dst] + pos] = src;
    }
}

// ---------------- fused MFMA QKV + edge counting ----------------
// blocks [0, qb): qkv (64 nodes/block); blocks [qb, qb+eb): degree count
// VKq[node] = 128B packed record: bytes [0..63] V fp8 (natural cols), [64..127] K fp8.
__global__ __launch_bounds__(256) void qkv_count(
    const float* __restrict__ x,
    const float* __restrict__ Wi, const float* __restrict__ bi,
    const float* __restrict__ Wq, const float* __restrict__ bq,
    const float* __restrict__ Wk, const float* __restrict__ bk,
    const float* __restrict__ Wv, const float* __restrict__ bv,
    float* __restrict__ Q, unsigned char* __restrict__ VKq,
    _Float16* __restrict__ Vh,
    const int* __restrict__ ei, int* __restrict__ deg,
    int E, int qb, int N)
{
    __shared__ unsigned short wit[64 * WIT_LD];
    __shared__ unsigned short w2t[192 * W2T_LD];
    __shared__ unsigned short hlds[64 * H_LD];
    if ((int)blockIdx.x >= qb) {
        int e = ((int)blockIdx.x - qb) * 256 + (int)threadIdx.x;
        if (e < E) atomicAdd(&deg[ei[E + e]], 1);   // dst = ei[1][e]
        return;
    }
    int t = threadIdx.x;
    #pragma unroll
    for (int i = 0; i < 32; ++i) {
        int g = t + i * 256;                       // 8192 = 128*64
        wit[(g & 63) * WIT_LD + (g >> 6)] = bf16r(Wi[g]);
    }
    #pragma unroll
    for (int i = 0; i < 16; ++i) {
        int g = t + i * 256;                       // 4096 = 64*64
        int k = g >> 6, n = g & 63;
        w2t[(n      ) * W2T_LD + k] = bf16r(Wq[g]);
        w2t[(n +  64) * W2T_LD + k] = bf16r(Wk[g]);
        w2t[(n + 128) * W2T_LD + k] = bf16r(Wv[g]);
    }
    __syncthreads();

    int lane = t & 63, w = t >> 6;
    int p = lane & 15, quad = lane >> 4;
    int mbase = blockIdx.x * 64 + w * 16;

    // ---- stage 1: h = relu(x@Wi + bi) ----
    short8 afrag[4];
    {
        int node = mbase + p;
        if (node >= N) node = N - 1;               // clamped read; stores guarded
        const float* xr = x + (size_t)node * F_IN + quad * 8;
        #pragma unroll
        for (int ks = 0; ks < 4; ++ks) {
            float4 a0 = *(const float4*)(xr + ks * 32);
            float4 a1 = *(const float4*)(xr + ks * 32 + 4);
            short8 f;
            f[0] = bf16r(a0.x); f[1] = bf16r(a0.y); f[2] = bf16r(a0.z); f[3] = bf16r(a0.w);
            f[4] = bf16r(a1.x); f[5] = bf16r(a1.y); f[6] = bf16r(a1.z); f[7] = bf16r(a1.w);
            afrag[ks] = f;
        }
    }
    #pragma unroll
    for (int nt = 0; nt < 4; ++nt) {
        f4v acc = {0.f, 0.f, 0.f, 0.f};
        #pragma unroll
        for (int ks = 0; ks < 4; ++ks) {
            short8 b = *(const short8*)&wit[(nt * 16 + p) * WIT_LD + ks * 32 + quad * 8];
            acc = __builtin_amdgcn_mfma_f32_16x16x32_bf16(afrag[ks], b, acc, 0, 0, 0);
        }
        float bb = bi[nt * 16 + p];
        #pragma unroll
        for (int r = 0; r < 4; ++r) {
            float hv = fmaxf(acc[r] + bb, 0.f);
            hlds[(w * 16 + quad * 4 + r) * H_LD + nt * 16 + p] = bf16r(hv);
        }
    }
    __syncthreads();

    // ---- stage 2: [Q|K|V] = h @ W2 + b ----
    short8 ha0 = *(const short8*)&hlds[(w * 16 + p) * H_LD + quad * 8];
    short8 ha1 = *(const short8*)&hlds[(w * 16 + p) * H_LD + 32 + quad * 8];
    int node_r = mbase + quad * 4;
    #pragma unroll
    for (int nt = 0; nt < 12; ++nt) {
        f4v acc = {0.f, 0.f, 0.f, 0.f};
        short8 b0 = *(const short8*)&w2t[(nt * 16 + p) * W2T_LD + quad * 8];
        short8 b1 = *(const short8*)&w2t[(nt * 16 + p) * W2T_LD + 32 + quad * 8];
        acc = __builtin_amdgcn_mfma_f32_16x16x32_bf16(ha0, b0, acc, 0, 0, 0);
        acc = __builtin_amdgcn_mfma_f32_16x16x32_bf16(ha1, b1, acc, 0, 0, 0);
        int col = nt * 16 + p;
        #pragma unroll
        for (int r = 0; r < 4; ++r) {
            int node = node_r + r;
            if (node >= N) continue;
            float v = acc[r];
            if (col < 64) {
                v += bq[col];
                Q[(size_t)node * 64 + col] = (v > 0.f) ? (1.f + v) : __expf(v);
            } else if (col < 128) {
                int c = col - 64;
                v += bk[c];
                float kv = (v > 0.f) ? (1.f + v) : __expf(v);
                VKq[(size_t)node * 128 + 64 + c] = f32_to_fp8(kv);
            } else {
                int c = col - 128;
                v += bv[c];
                Vh[(size_t)node * 64 + c] = (_Float16)v;       // f16 copy for hop-0
                VKq[(size_t)node * 128 + c] = f32_to_fp8(v);   // fp8 copy for gather
            }
        }
    }
}

// M layout: per node one merged 640B row (512B fp4 payload || 128B SK), NATURAL
// columns: lane (h*16+p), nibble j = M[h][d=p][c=j]/scale; SK = {scale fp8, K fp8}.

// ---------------- hop 1: rows1 = A (K ⊗ V) from packed 128B VK records ----------------
// also writes the hop-0 term: hidden = V*temp[:,0] + gamma1*(...)
// 128-thread blocks (2 waves, 2 nodes): finer occupancy-refill granularity.
__global__ __launch_bounds__(128) void hop1_all(
    const float* __restrict__ Q, const unsigned char* __restrict__ VKq,
    const _Float16* __restrict__ Vh,
    const int* __restrict__ offsets, const int* __restrict__ csr,
    const float* __restrict__ temp, const float* __restrict__ hopwise,
    unsigned char* __restrict__ rows1, float* __restrict__ hidden, int N)
{
    int lane = threadIdx.x & 63;
    int node = blockIdx.x * 2 + (threadIdx.x >> 6);
    if (node >= N) return;
    int h = lane >> 4;
    float gh = gamma_for(temp, hopwise, h, 1);
    // hoisted independent loads: latency hides under the gather loop
    float h0 = (float)Vh[(size_t)node * 64 + lane] * temp[h * 4];
    float qd = Q[(size_t)node * 64 + lane];
    f2 u2[8];
    #pragma unroll
    for (int j = 0; j < 8; ++j) u2[j] = f2{0.f, 0.f};
    float kacc = 0.f;
    // scalarized loop bounds: loop control + csr + row bases on SALU/SMEM
    int beg = uni(offsets[node]), end = uni(offsets[node + 1]);
    int t = beg;
    // 4-edge batches: 1 cache line per edge (16B broadcast V + 1B K, same 128B rec)
    for (; t + 3 < end; t += 4) {
        int s0 = uni(csr[t]),     s1 = uni(csr[t + 1]);
        int s2 = uni(csr[t + 2]), s3 = uni(csr[t + 3]);
        const unsigned char* b0 = VKq + (size_t)s0 * 128;
        const unsigned char* b1 = VKq + (size_t)s1 * 128;
        const unsigned char* b2 = VKq + (size_t)s2 * 128;
        const unsigned char* b3 = VKq + (size_t)s3 * 128;
        uint4 v0 = *(const uint4*)(b0 + h * 16);
        uint4 v1 = *(const uint4*)(b1 + h * 16);
        uint4 v2 = *(const uint4*)(b2 + h * 16);
        uint4 v3 = *(const uint4*)(b3 + h * 16);
        unsigned char k0 = b0[64 + lane];
        unsigned char k1 = b1[64 + lane];
        unsigned char k2 = b2[64 + lane];
        unsigned char k3 = b3[64 + lane];
        acc_edge1(u2, kacc, v0, k0);
        acc_edge1(u2, kacc, v1, k1);
        acc_edge1(u2, kacc, v2, k2);
        acc_edge1(u2, kacc, v3, k3);
    }
    for (; t < end; ++t) {
        int s = uni(csr[t]);
        const unsigned char* b = VKq + (size_t)s * 128;
        uint4 vw = *(const uint4*)(b + h * 16);
        unsigned char kk = b[64 + lane];
        acc_edge1(u2, kacc, vw, kk);
    }
    float u[16];
    #pragma unroll
    for (int j = 0; j < 8; ++j) { u[2 * j] = u2[j].x; u[2 * j + 1] = u2[j].y; }
    store_m_row(rows1 + (size_t)node * MROW, lane, u, kacc);
    #pragma unroll
    for (int j = 0; j < 16; ++j) u[j] *= qd;
    reduce_scatter16(u, lane & 15);
    float g = gh / den16(qd, kacc);
    hidden[(size_t)node * 64 + lane] = h0 + g * u[0];
}

// ---------------- hops 2/3: merged-row fp4 M gather ----------------
// STORE=true : hop 2 — store rows2, accumulate into hidden
// STORE=false: hop 3 — no store; fuse the output projection (out = hidden@Wo+bo)
template<bool STORE>
__global__ __launch_bounds__(128) void hop23_all(
    const float* __restrict__ Q, const unsigned char* __restrict__ rowsp,
    const int* __restrict__ offsets, const int* __restrict__ csr,
    const float* __restrict__ temp, const float* __restrict__ hopwise,
    unsigned char* __restrict__ rowsn, float* __restrict__ hidden,
    const float* __restrict__ Wo, const float* __restrict__ bo,
    float* __restrict__ out, int N, int hop)
{
    int lane = threadIdx.x & 63;
    int node = blockIdx.x * 2 + (threadIdx.x >> 6);
    if (node >= N) return;
    float gh = gamma_for(temp, hopwise, lane >> 4, hop);
    // hoisted independent epilogue loads — latency hides under the gather
    float qd  = Q[(size_t)node * 64 + lane];
    float hv0 = STORE ? 0.f : hidden[(size_t)node * 64 + lane];
    f2 u2[8];
    #pragma unroll
    for (int j = 0; j < 8; ++j) u2[j] = f2{0.f, 0.f};
    float kacc = 0.f;
    int mo = lane * 8, so = SKOFF + lane * 2;      // loop-invariant lane offsets
    // scalarized loop bounds + csr + row bases (wave-uniform) → SALU/SMEM
    int beg = uni(offsets[node]), end = uni(offsets[node + 1]);
    int t = beg;
    // 4-edge batches (r3 schedule) over merged 640B rows: both loads of an edge
    // hit the same contiguous row (one locality region, one page)
    for (; t + 3 < end; t += 4) {
        int s0 = uni(csr[t]),     s1 = uni(csr[t + 1]);
        int s2 = uni(csr[t + 2]), s3 = uni(csr[t + 3]);
        const unsigned char* r0 = rowsp + (size_t)s0 * MROW;
        const unsigned char* r1 = rowsp + (size_t)s1 * MROW;
        const unsigned char* r2 = rowsp + (size_t)s2 * MROW;
        const unsigned char* r3 = rowsp + (size_t)s3 * MROW;
        uint2 w0 = *(const uint2*)(r0 + mo);
        uint2 w1 = *(const uint2*)(r1 + mo);
        uint2 w2 = *(const uint2*)(r2 + mo);
        uint2 w3 = *(const uint2*)(r3 + mo);
        unsigned short k0 = *(const unsigned short*)(r0 + so);
        unsigned short k1 = *(const unsigned short*)(r1 + so);
        unsigned short k2 = *(const unsigned short*)(r2 + so);
        unsigned short k3 = *(const unsigned short*)(r3 + so);
        acc_edge23(u2, kacc, w0, k0);
        acc_edge23(u2, kacc, w1, k1);
        acc_edge23(u2, kacc, w2, k2);
        acc_edge23(u2, kacc, w3, k3);
    }
    for (; t < end; ++t) {
        int sn = uni(csr[t]);
        const unsigned char* r = rowsp + (size_t)sn * MROW;
        uint2 w = *(const uint2*)(r + mo);
        unsigned short skr = *(const unsigned short*)(r + so);
        acc_edge23(u2, kacc, w, skr);
    }
    float u[16];
    #pragma unroll
    for (int j = 0; j < 8; ++j) { u[2 * j] = u2[j].x; u[2 * j + 1] = u2[j].y; }
    if constexpr (STORE) store_m_row(rowsn + (size_t)node * MROW, lane, u, kacc);
    #pragma unroll
    for (int j = 0; j < 16; ++j) u[j] *= qd;
    reduce_scatter16(u, lane & 15);
    float g = gh / den16(qd, kacc);
    if constexpr (STORE) {
        hidden[(size_t)node * 64 + lane] += g * u[0];
    } else {
        // fused output projection: each lane holds one hidden element of the row.
        // Wo row loaded AFTER the gather loop — keeps it out of the hot-loop
        // register budget (round-1 lesson: 16 live VGPRs there cost occupancy).
        float wrow[16];
        {
            const f4v* wp = (const f4v*)(Wo + (size_t)lane * 16);
            f4v a = wp[0], b = wp[1], c = wp[2], d = wp[3];
            wrow[0]=a[0]; wrow[1]=a[1]; wrow[2]=a[2]; wrow[3]=a[3];
            wrow[4]=b[0]; wrow[5]=b[1]; wrow[6]=b[2]; wrow[7]=b[3];
            wrow[8]=c[0]; wrow[9]=c[1]; wrow[10]=c[2]; wrow[11]=c[3];
            wrow[12]=d[0]; wrow[13]=d[1]; wrow[14]=d[2]; wrow[15]=d[3];
        }
        float hv = hv0 + g * u[0];
        float o[16];
        #pragma unroll
        for (int j = 0; j < 16; ++j) o[j] = hv * wrow[j];
        reduce_scatter16(o, lane & 15);          // per-quad partials, col = lane&15
        float r = o[0];
        r += __shfl_xor(r, 16, 64);              // sum the 4 quads
        r += __shfl_xor(r, 32, 64);
        if (lane < 16) out[(size_t)node * 16 + lane] = r + bo[lane];
    }
}

extern "C" void kernel_launch(void* const* d_in, const int* in_sizes, int n_in,
                              void* d_out, int out_size, void* d_ws, size_t ws_size,
                              hipStream_t stream) {
    const float* x       = (const float*)d_in[0];
    const int*   ei      = (const int*)  d_in[1];
    const float* Wi      = (const float*)d_in[2];
    const float* bi      = (const float*)d_in[3];
    const float* Wq      = (const float*)d_in[4];
    const float* bq      = (const float*)d_in[5];
    const float* Wk      = (const float*)d_in[6];
    const float* bk      = (const float*)d_in[7];
    const float* Wv      = (const float*)d_in[8];
    const float* bv      = (const float*)d_in[9];
    const float* Wo      = (const float*)d_in[10];
    const float* bo      = (const float*)d_in[11];
    const float* hopwise = (const float*)d_in[12];
    const float* temp    = (const float*)d_in[13];

    const int N = in_sizes[0] / F_IN;
    const int E = in_sizes[1] / 2;

    char* ws = (char*)d_ws;
    size_t off = 0;
    auto take = [&](size_t bytes) -> char* {
        char* p = ws + off;
        off += (bytes + 255) & ~(size_t)255;
        return p;
    };
    float*          Q      = (float*)take((size_t)N * 64 * 4);
    _Float16*       Vh     = (_Float16*)take((size_t)N * 64 * 2);
    float*          hidden = (float*)take((size_t)N * 64 * 4);
    unsigned char*  VKq    = (unsigned char*)take((size_t)N * 128);
    int*            degcur = (int*)take((size_t)2 * N * 4);   // deg | cursor
    int*            offs   = (int*)take((size_t)(N + 1) * 4);
    int*            csr    = (int*)take((size_t)E * 4);
    int             nb     = (N + 4095) / 4096;
    int*            bsum   = (int*)take((size_t)nb * 4);
    unsigned char*  rows1  = (unsigned char*)take((size_t)N * MROW);
    unsigned char*  rows2  = (unsigned char*)take((size_t)N * MROW);

    int* deg    = degcur;
    int* cursor = degcur + N;

    hipMemsetAsync(degcur, 0, (size_t)2 * N * 4, stream);

    int eb = (E + 255) / 256;
    int qb = (N + 63) / 64;
    // fused: qkv (qb blocks) + degree count (eb blocks)
    qkv_count<<<qb + eb, 256, 0, stream>>>(x, Wi, bi, Wq, bq, Wk, bk, Wv, bv,
                                           Q, VKq, Vh,
                                           ei, deg, E, qb, N);
    scan_a<<<nb, 1024, 0, stream>>>(deg, offs, bsum, N);
    scan_c<<<(N + 255) / 256, 256, 0, stream>>>(offs, bsum, nb, N);
    scatter_kernel<<<eb, 256, 0, stream>>>(ei, offs, cursor, csr, E);

    int nb2 = (N + 1) / 2;
    hop1_all<<<nb2, 128, 0, stream>>>(Q, VKq, Vh, offs, csr, temp, hopwise,
                                      rows1, hidden, N);
    hop23_all<true ><<<nb2, 128, 0, stream>>>(Q, rows1, offs, csr, temp, hopwise,
                                              rows2, hidden,
                                              (const float*)nullptr, (const float*)nullptr,
                                              (float*)nullptr, N, 2);
    hop23_all<false><<<nb2, 128, 0, stream>>>(Q, rows2, offs, csr, temp, hopwise,
                                              (unsigned char*)nullptr, hidden,
                                              Wo, bo, (float*)d_out, N, 3);
}